// Round 1
// baseline (192.276 us; speedup 1.0000x reference)
//
#include <hip/hip_runtime.h>

// MoreParamDenseQConv1D: quantum-circuit conv1d.
// B=16, C_in=4, L=2048, K=8, OUT_CH=8, N_LAYERS=2, N_QUBITS=7, DIM=128.
// One wave (64 lanes) evolves one (row, oc) 128-dim complex state:
// 2 complex amps per lane. The acting qubit is kept in the "slot" axis via
// 13 slot<->lane-bit re-pairings (2 ds_bpermute each), so every gate is a
// clean in-lane 16-FMA complex 2x2 matvec with wave-uniform coefficients.

#define L_OUT 2041
#define N_ROWS (16 * L_OUT)   // 32656 blocks, 8 waves each = 261248 tasks

__device__ __forceinline__ float bperm(int addr, float v) {
    return __int_as_float(__builtin_amdgcn_ds_bpermute(addr, __float_as_int(v)));
}

__device__ __forceinline__ float wave_sum(float v, int lane) {
#pragma unroll
    for (int m = 32; m; m >>= 1)
        v += bperm((lane ^ m) << 2, v);
    return v;
}

// Per gate store 4 floats: u00r, u00i, u10r, u10i.
// u00 = conj(ep)*cb, u10 = em*sb, u01 = -conj(u10), u11 = conj(u00).
__device__ __forceinline__ void gate_coeffs(const float* __restrict__ thetas, int i,
                                            float* o) {
    float a = thetas[i * 3 + 0], b = thetas[i * 3 + 1], g = thetas[i * 3 + 2];
    float sb = sinf(b * 0.5f), cb = cosf(b * 0.5f);
    float sp, cp, sm, cm;
    sincosf((a + g) * 0.5f, &sp, &cp);
    sincosf((a - g) * 0.5f, &sm, &cm);
    o[0] = cp * cb;
    o[1] = -sp * cb;
    o[2] = cm * sb;
    o[3] = sm * sb;
}

__global__ void prep_gates_k(const float* __restrict__ thetas, float* __restrict__ gates) {
    int i = threadIdx.x;
    if (i >= 112) return;  // (oc, l, q) = i = oc*14 + l*7 + q
    float o[4];
    gate_coeffs(thetas, i, o);
    gates[i * 4 + 0] = o[0];
    gates[i * 4 + 1] = o[1];
    gates[i * 4 + 2] = o[2];
    gates[i * 4 + 3] = o[3];
}

template <bool USE_WS>
__global__ __launch_bounds__(512) void qconv_k(const float* __restrict__ x,
                                               const float* __restrict__ thetas,
                                               const float* __restrict__ gates_g,
                                               float* __restrict__ out) {
    int lane = threadIdx.x & 63;
    int wv = threadIdx.x >> 6;                       // 0..7 == out-channel
    int oc = __builtin_amdgcn_readfirstlane(wv);

    const float* gb;
    if constexpr (!USE_WS) {
        __shared__ float gl[112 * 4];
        int t = threadIdx.x;
        if (t < 112) {
            float o[4];
            gate_coeffs(thetas, t, o);
            gl[t * 4 + 0] = o[0];
            gl[t * 4 + 1] = o[1];
            gl[t * 4 + 2] = o[2];
            gl[t * 4 + 3] = o[3];
        }
        __syncthreads();
        gb = gl + oc * 56;
    } else {
        gb = gates_g + oc * 56;   // 14 gates * 4 floats
    }

    int row = blockIdx.x;          // 0..32655
    int b = row / L_OUT;
    int lout = row - b * L_OUT;

    // window load: amp[j] = x[b, j>>3, lout + (j&7)] for j<32, else 0
    float xv = 0.f;
    if (lane < 32) {
        int c = lane >> 3, k = lane & 7;
        xv = x[(b * 4 + c) * 2048 + lout + k];
    }
    float rn = rsqrtf(wave_sum(xv * xv, lane));

    // state: v0 = amp[lane] (slot bit = amp bit 6 = 0), v1 = amp[lane+64] = 0
    float v0r = xv * rn, v0i = 0.f, v1r = 0.f, v1i = 0.f;
    float ur, ui, vr, vi;

#define GLOAD(gi)                                           \
    {                                                       \
        float4 gg = *(const float4*)(gb + (gi) * 4);        \
        ur = gg.x; ui = gg.y; vr = gg.z; vi = gg.w;         \
    }
// new0 = u00*a0 + u01*a1 ; new1 = u10*a0 + u11*a1  (u01=-conj(u10), u11=conj(u00))
#define GAPPLY()                                            \
    {                                                       \
        float n0r = ur * v0r - ui * v0i - vr * v1r - vi * v1i; \
        float n0i = ur * v0i + ui * v0r + vi * v1r - vr * v1i; \
        float n1r = vr * v0r - vi * v0i + ur * v1r + ui * v1i; \
        float n1i = vr * v0i + vi * v0r + ur * v1i - ui * v1r; \
        v0r = n0r; v0i = n0i; v1r = n1r; v1i = n1i;         \
    }
// exchange slot axis with lane-bit (m): hi lanes send v0, lo lanes send v1
#define REPAIR(m)                                           \
    {                                                       \
        bool hi = (lane & (m)) != 0;                        \
        int ad = (lane ^ (m)) << 2;                         \
        float sr = hi ? v0r : v1r;                          \
        float si = hi ? v0i : v1i;                          \
        float rr = bperm(ad, sr);                           \
        float ri = bperm(ad, si);                           \
        v0r = hi ? rr : v0r;                                \
        v0i = hi ? ri : v0i;                                \
        v1r = hi ? v1r : rr;                                \
        v1i = hi ? v1i : ri;                                \
    }

    // ---- layer 1 ----
    // gate q=0 (amp bit 6 in slot): a1 = 0, a0 real
    GLOAD(0);
    {
        float xx = v0r;
        v0r = ur * xx; v0i = ui * xx; v1r = vr * xx; v1i = vi * xx;
    }
    REPAIR(32);
    // gate q=1: slot = amp bit 5; those amps are still all-zero in slot 1
    GLOAD(1);
    {
        float x0r = v0r, x0i = v0i;
        v0r = ur * x0r - ui * x0i; v0i = ur * x0i + ui * x0r;
        v1r = vr * x0r - vi * x0i; v1i = vr * x0i + vi * x0r;
    }
    REPAIR(16); GLOAD(2); GAPPLY();
    REPAIR(8);  GLOAD(3); GAPPLY();
    REPAIR(4);  GLOAD(4); GAPPLY();
    REPAIR(2);  GLOAD(5); GAPPLY();
    REPAIR(1);  GLOAD(6); GAPPLY();

    // entangle diag: sign(popcount) — invariant under the bit permutation
    int kc = __popc(lane);
    float s0 = ((kc >> 1) & 1) ? -1.f : 1.f;
    float s1 = (((kc + 1) >> 1) & 1) ? -1.f : 1.f;
    v0r *= s0; v0i *= s0; v1r *= s1; v1i *= s1;

    // ---- layer 2 ----  (mapping after L1: S:amp0, L5:amp6, L4:amp5, ..., L0:amp1)
    REPAIR(32); GLOAD(7);  GAPPLY();   // amp6
    REPAIR(16); GLOAD(8);  GAPPLY();   // amp5
    REPAIR(8);  GLOAD(9);  GAPPLY();   // amp4
    REPAIR(4);  GLOAD(10); GAPPLY();   // amp3
    REPAIR(2);  GLOAD(11); GAPPLY();   // amp2
    REPAIR(1);  GLOAD(12); GAPPLY();   // amp1
    REPAIR(32); GLOAD(13); GAPPLY();   // amp0
    v0r *= s0; v0i *= s0; v1r *= s1; v1i *= s1;

    // measurement: z0 sign = -1 iff amp bit6 == 1; amp bit6 now lives on lane bit 4
    float e = v0r * v0r + v0i * v0i + v1r * v1r + v1i * v1i;
    e = (lane & 16) ? -e : e;
    e = wave_sum(e, lane);
    if (lane == 0) out[(b * 8 + oc) * L_OUT + lout] = e;
#undef GLOAD
#undef GAPPLY
#undef REPAIR
}

extern "C" void kernel_launch(void* const* d_in, const int* in_sizes, int n_in,
                              void* d_out, int out_size, void* d_ws, size_t ws_size,
                              hipStream_t stream) {
    const float* x = (const float*)d_in[0];
    const float* thetas = (const float*)d_in[1];
    float* out = (float*)d_out;

    if (ws_size >= 112 * 4 * sizeof(float)) {
        float* gates = (float*)d_ws;
        prep_gates_k<<<1, 128, 0, stream>>>(thetas, gates);
        qconv_k<true><<<N_ROWS, 512, 0, stream>>>(x, thetas, gates, out);
    } else {
        qconv_k<false><<<N_ROWS, 512, 0, stream>>>(x, thetas, nullptr, out);
    }
}